// Round 15
// baseline (186.975 us; speedup 1.0000x reference)
//
#include <hip/hip_runtime.h>
#include <hip/hip_bf16.h>

// Problem constants
#define Bsz 16
#define Lsz 512
#define Dsz 768
#define Tsz 12
#define Asz 64
#define N1  1536   // Tsz*Asz*2
#define Msz 8192   // Bsz*Lsz

typedef __bf16 bf16;
typedef bf16 bf16x2 __attribute__((ext_vector_type(2)));
typedef bf16 bf16x4 __attribute__((ext_vector_type(4)));
typedef bf16 bf16x8 __attribute__((ext_vector_type(8)));
typedef float f32x4 __attribute__((ext_vector_type(4)));
typedef unsigned long long u64;
typedef unsigned int u32;

__device__ inline void load_lds16(const void* g, void* l) {
    __builtin_amdgcn_global_load_lds((const __attribute__((address_space(1))) void*)g,
                                     (__attribute__((address_space(3))) void*)l, 16, 0, 0);
}

// ---- prep (small): cvt_w | mask bits | zero sync counters ----
__global__ __launch_bounds__(256) void prep_kernel(
    const float* __restrict__ W, const int* __restrict__ mask,
    bf16* __restrict__ Wt, u64* __restrict__ Mbits, u32* __restrict__ cnt) {
    int blk = blockIdx.x;
    if (blk < 576) {                        // cvt_w: N1*(Dsz/8) threads
        int tid = blk * 256 + threadIdx.x;
        int n  = tid % N1;
        int k0 = (tid / N1) * 8;
        bf16x8 o;
#pragma unroll
        for (int j = 0; j < 8; ++j) o[j] = (bf16)W[(size_t)(k0 + j) * N1 + n];
        *(bf16x8*)(Wt + (size_t)n * Dsz + k0) = o;
    } else if (blk < 608) {                 // mask bits: 16*512 threads
        int tid = (blk - 576) * 256 + threadIdx.x;
        u64 bal = __ballot(mask[tid] > 0);
        if ((tid & 63) == 0) Mbits[tid >> 6] = bal;
    } else {                                // zero the 16 per-b counters
        if (threadIdx.x < 16) cnt[threadIdx.x] = 0;
    }
}

// convert 32 rows [r0, r0+32) of fp32 panel b into bf16 Abf (coalesced)
__device__ __forceinline__ void cvt_slice(
    const float* __restrict__ inA, bf16* __restrict__ Abf, int b, int r0, int tid) {
    const float* src = inA + ((size_t)b * Lsz + r0) * Dsz;
    bf16* dst = Abf + ((size_t)b * Lsz + r0) * Dsz;
#pragma unroll
    for (int i = 0; i < 12; ++i) {          // 32*768/4 = 6144 float4
        const int idx = i * 512 + tid;
        float4 v = ((const float4*)src)[idx];
        bf16x4 o;
        o[0] = (bf16)v.x; o[1] = (bf16)v.y; o[2] = (bf16)v.z; o[3] = (bf16)v.w;
        ((bf16x4*)dst)[idx] = o;
    }
}

// ---- fused: per-block A-slice cvt + per-b spin-sync, then
//   blocks 0..191: proj (R7 bf16 staging) + 3 lower tiles + rope + upper QK;
//   blocks 192..255: 25 lower tiles x 3 z fills.
// 144KB LDS + 512 thr => exactly 1 block/CU; 256 blocks = 256 CUs co-resident.
// Producers of panel b: 12 head-blocks (rows th*32) + 4 fill blocks on the
// same XCD (rows 384..511). Counters device-scope; threadfence before add.
#define PBUF 40960   // A 32768 + W 8192 per staging buffer
__global__ __launch_bounds__(512) void fused_kernel(
    const float* __restrict__ inA, bf16* __restrict__ Abf,
    const bf16* __restrict__ Wt, const float* __restrict__ bias,
    const u64* __restrict__ Mbits, u32* __restrict__ cnt,
    float* __restrict__ out) {
    __shared__ char smem[147456];
    const int bid = blockIdx.x;
    const int tid = threadIdx.x;

    if (bid >= 192) {
        // -------- fill role --------
        const int w = bid - 192;
        // cvt duty: panel b on this block's XCD, rows 384..511
        const int bb = 2 * (w & 7) + ((w >> 3) & 1);
        cvt_slice(inA, Abf, bb, (12 + (w >> 4)) * 32, tid);
        __threadfence();
        __syncthreads();
        if (tid == 0) atomicAdd(&cnt[bb], 1u);

        // fills: tiles p=3..27 of 3 z each
        const f32x4 f = {-1e12f, -1e12f, -1e12f, -1e12f};
        const u64 itlo = 0x6555554444333221ull, ithi = 0x0000777777766666ull;
        const u64 jtlo = 0x0432103210210100ull, jthi = 0x0000654321054321ull;
        for (int zz = 0; zz < 3; ++zz) {
            float* ob = out + (size_t)(w * 3 + zz) * Lsz * Lsz;
#pragma unroll
            for (int p = 3; p < 28; ++p) {
                const int it = (int)(((p < 16) ? (itlo >> (4 * p)) : (ithi >> (4 * (p - 16)))) & 15);
                const int jt = (int)(((p < 16) ? (jtlo >> (4 * p)) : (jthi >> (4 * (p - 16)))) & 15);
#pragma unroll
                for (int rep = 0; rep < 2; ++rep) {
                    const int idx = rep * 512 + tid;
                    const int r = idx >> 4, c = (idx & 15) << 2;
                    *(f32x4*)(ob + (size_t)(it * 64 + r) * Lsz + jt * 64 + c) = f;
                }
            }
        }
        return;
    }

    // ---------------- compute role ----------------
    bf16* Xq = (bf16*)smem;                  // [512][72]
    bf16* Xk = (bf16*)(smem + 73728);        // [512][72]

    const int z  = (bid & 7) * 24 + (bid >> 3);   // XCD-chunked
    const int b  = z / Tsz, th = z % Tsz;

    // cvt duty: rows th*32 of own panel
    cvt_slice(inA, Abf, b, th * 32, tid);
    __threadfence();
    __syncthreads();
    if (tid == 0) {
        atomicAdd(&cnt[b], 1u);
        while (atomicAdd(&cnt[b], 0u) < 16u) { }     // spin: panel b complete
    }
    __syncthreads();
    __threadfence();

    const int wave = tid >> 6, lane = tid & 63;
    const int l15 = lane & 15, hi = lane >> 4;
    const int wm = wave >> 1, wn = wave & 1;

    const bf16* Ab = Abf + (size_t)b * Lsz * Dsz;
    const bf16* Wb = Wt + (size_t)th * 128 * Dsz;
    float* ob = out + (size_t)z * Lsz * Lsz;
    const int lq = lane >> 2;
    const int schunk = ((lane & 3) ^ ((lane >> 3) & 3)) * 8;   // swizzled src chunk
    const int dchunk = (lane & 3) * 8;                          // linear dest chunk
    const int koff = (hi ^ ((l15 >> 1) & 3)) * 16;              // swizzled frag read

    // ---------- phase 1: projection 512x128 = A @ W_head^T (R7 structure) ----------
    f32x4 acc[8][4] = {};

#define PSTAGE(buf, kk)                                                         \
    do {                                                                        \
        bf16* As = (bf16*)(smem + (buf) * PBUF);                                \
        bf16* Ws = (bf16*)(smem + (buf) * PBUF + 32768);                        \
        _Pragma("unroll")                                                       \
        for (int i = 0; i < 4; ++i) {                                           \
            int ra = wave * 64 + i * 16 + lq;                                   \
            load_lds16(Ab + (size_t)ra * Dsz + (kk) + schunk, As + ra * 32 + dchunk); \
        }                                                                       \
        int rw = wave * 16 + lq;                                                \
        load_lds16(Wb + (size_t)rw * Dsz + (kk) + schunk, Ws + rw * 32 + dchunk); \
    } while (0)

    PSTAGE(0, 0);
    PSTAGE(1, 32);
    asm volatile("s_waitcnt vmcnt(5)" ::: "memory");
    __builtin_amdgcn_s_barrier();

    int cur = 0;
    for (int t = 0; t < 24; ++t) {
        int stg = cur + 2; if (stg >= 3) stg -= 3;
        if (t + 2 < 24) PSTAGE(stg, (t + 2) * 32);

        const char* As = smem + cur * PBUF;
        const char* Ws = smem + cur * PBUF + 32768;
        bf16x8 af[8], bw[4];
#pragma unroll
        for (int mf = 0; mf < 8; ++mf)
            af[mf] = *(const bf16x8*)(As + (wm * 128 + mf * 16 + l15) * 64 + koff);
#pragma unroll
        for (int nf = 0; nf < 4; ++nf)
            bw[nf] = *(const bf16x8*)(Ws + (wn * 64 + nf * 16 + l15) * 64 + koff);
#pragma unroll
        for (int mf = 0; mf < 8; ++mf)
#pragma unroll
            for (int nf = 0; nf < 4; ++nf)
                acc[mf][nf] = __builtin_amdgcn_mfma_f32_16x16x32_bf16(af[mf], bw[nf], acc[mf][nf], 0, 0, 0);

        if (t + 1 < 24) {
            if (t + 2 < 24) asm volatile("s_waitcnt vmcnt(5)" ::: "memory");
            else            asm volatile("s_waitcnt vmcnt(0)" ::: "memory");
            __builtin_amdgcn_s_barrier();
        }
        cur = cur + 1; if (cur >= 3) cur -= 3;
    }
#undef PSTAGE

    // ---------- compute-side fill: waves 0..2 write lower tiles (1,0),(2,0),(2,1) ----------
    if (wave < 3) {
        const int fit = (wave == 0) ? 1 : 2;
        const int fjt = (wave == 2) ? 1 : 0;
        const f32x4 f = {-1e12f, -1e12f, -1e12f, -1e12f};
#pragma unroll
        for (int c = 0; c < 16; ++c) {
            const int idx = c * 64 + lane;
            const int r = idx >> 4, col = (idx & 15) << 2;
            *(f32x4*)(ob + (size_t)(fit * 64 + r) * Lsz + fjt * 64 + col) = f;
        }
    }

    __syncthreads();    // staging dead; smem becomes planes

    // ---------- phase 2: acc (+bias) -> q/k planes ----------
    {
        const int r0 = hi * 4;
#pragma unroll
        for (int nf = 0; nf < 4; ++nf) {
            const int c = wn * 64 + nf * 16 + l15;
            const float bv = bias[th * 128 + c];
            bf16* P = (c & 1) ? Xk : Xq;
            const int a = c >> 1;
#pragma unroll
            for (int mf = 0; mf < 8; ++mf) {
                const int rwp = wm * 128 + mf * 16 + r0;
#pragma unroll
                for (int r = 0; r < 4; ++r)
                    P[(rwp + r) * 72 + a] = (bf16)(acc[mf][nf][r] + bv);
            }
        }
    }
    __syncthreads();

    // ---------- phase 3: rope in place, inline trig (thread = row l) ----------
    {
        const int l = tid;
        float tcv[32], tsv[32];
#pragma unroll
        for (int h = 0; h < 32; ++h) {
            const float theta = expf(-0.28782313662425575f * (float)h);  // folds
            sincosf((float)l * theta, &tsv[h], &tcv[h]);
        }
#pragma unroll
        for (int pl = 0; pl < 2; ++pl) {
            bf16* P = pl ? Xk : Xq;
            float v[64];
#pragma unroll
            for (int c8 = 0; c8 < 8; ++c8) {
                bf16x8 x = *(const bf16x8*)(P + l * 72 + c8 * 8);
#pragma unroll
                for (int j = 0; j < 8; ++j) v[c8 * 8 + j] = (float)x[j];
            }
#pragma unroll
            for (int c8 = 0; c8 < 8; ++c8) {
                bf16x8 o;
#pragma unroll
                for (int j = 0; j < 8; ++j) {
                    const int a  = c8 * 8 + j;
                    const int a2 = (a < 32) ? (2 * a + 1) : (2 * (a - 32));
                    const float sg = (a < 32) ? -1.f : 1.f;
                    o[j] = (bf16)(v[a] * tcv[a >> 1] + sg * v[a2] * tsv[a >> 1]);
                }
                *(bf16x8*)(P + l * 72 + c8 * 8) = o;
            }
        }
    }
    __syncthreads();

    // ---------- phase 4: QK^T + mask, upper tiles only ----------
    const u64* mb = Mbits + b * 8;
#pragma unroll
    for (int s = 0; s < 8; ++s) {
        const int it = s, jt = (wave - s) & 7;    // (it+jt)%8==wave
        if (jt < it) continue;
        const int i0 = it * 64, j0 = jt * 64;
        const u64 jb = mb[jt], ib = mb[it];
        bf16x8 k0[4], k1[4];
#pragma unroll
        for (int ct = 0; ct < 4; ++ct) {
            const int jr = j0 + ct * 16 + l15;
            k0[ct] = *(const bf16x8*)(Xk + jr * 72 + hi * 8);
            k1[ct] = *(const bf16x8*)(Xk + jr * 72 + 32 + hi * 8);
        }
#pragma unroll
        for (int is = 0; is < 4; ++is) {
            const int ir = i0 + is * 16 + l15;
            bf16x8 q0 = *(const bf16x8*)(Xq + ir * 72 + hi * 8);
            bf16x8 q1 = *(const bf16x8*)(Xq + ir * 72 + 32 + hi * 8);
            f32x4 a4[4] = {};
#pragma unroll
            for (int ct = 0; ct < 4; ++ct) {
                a4[ct] = __builtin_amdgcn_mfma_f32_16x16x32_bf16(k0[ct], q0, a4[ct], 0, 0, 0);
                a4[ct] = __builtin_amdgcn_mfma_f32_16x16x32_bf16(k1[ct], q1, a4[ct], 0, 0, 0);
            }
            const bool mi = (ib >> (is * 16 + l15)) & 1;
#pragma unroll
            for (int ct = 0; ct < 4; ++ct) {
                const int jbase = ct * 16 + hi * 4;
                f32x4 vv;
#pragma unroll
                for (int r = 0; r < 4; ++r) {
                    const int j = j0 + jbase + r;
                    const bool keep = mi && ((jb >> (jbase + r)) & 1) && (ir <= j);
                    vv[r] = keep ? a4[ct][r] : -1e12f;
                }
                *(f32x4*)(ob + (size_t)ir * Lsz + j0 + jbase) = vv;
            }
        }
    }
}

extern "C" void kernel_launch(void* const* d_in, const int* in_sizes, int n_in,
                              void* d_out, int out_size, void* d_ws, size_t ws_size,
                              hipStream_t stream) {
    const float* in_f  = (const float*)d_in[0];
    const int*   amask = (const int*)d_in[1];
    const float* W     = (const float*)d_in[2];
    const float* bias  = (const float*)d_in[3];
    float* out = (float*)d_out;

    char* ws = (char*)d_ws;
    bf16* Abf    = (bf16*)ws;                                // 12,582,912 B
    bf16* Wt     = (bf16*)(ws + 12582912);                   //  2,359,296 B
    u64*  Mbits  = (u64*)(ws + 14942208);                    //      1,024 B
    u32*  cnt    = (u32*)(ws + 14943232);                    //         64 B

    prep_kernel<<<609, 256, 0, stream>>>(W, amask, Wt, Mbits, cnt);
    fused_kernel<<<256, 512, 0, stream>>>(in_f, Abf, Wt, bias, Mbits, cnt, out);
}